// Round 9
// baseline (774.028 us; speedup 1.0000x reference)
//
#include <hip/hip_runtime.h>

// Masked dot-product attention. INPUTS float32, OUTPUT float32.
// B=32, Q=K=2048, D=128.
// R9: revert R8's spill (launch_bounds(256,3), ~148 unified regs OK);
// XCD-partitioned work queues (8 queues, batch%8 affinity, batch-major
// order, work stealing) so staging hits per-XCD L2; counted-vmcnt
// barrier #1 keeps next K tile in flight through PV. Keeps pre-swizzled
// tiles + global_load_lds, fixed-m softmax, cvt_pk+permlane P-repack,
// tree-sum l, chunk-split C=8 + combine.

using bf16   = __bf16;
using bf16x4 = __attribute__((ext_vector_type(4)))  __bf16;
using bf16x8 = __attribute__((ext_vector_type(8)))  __bf16;
using f32x4  = __attribute__((ext_vector_type(4)))  float;
using f32x16 = __attribute__((ext_vector_type(16))) float;

constexpr int BATCH = 32;
constexpr int QLEN  = 2048;
constexpr int KLEN  = 2048;
constexpr int DH    = 128;
constexpr int QBLK  = 128;          // q-rows per item (4 waves x 32)
constexpr int KVBLK = 64;           // kv tile
constexpr int NT    = KLEN / KVBLK; // 32
constexpr int CHUNK = 8;            // max KV tiles per item (split granularity)
constexpr int QCAP  = 256;          // max items per XCD queue (4*4*16)
constexpr int MAXSLOTS = 96;

// ---- workspace layout (byte offsets) ----
constexpr size_t OFF_KB    = 0;                       // 16 MB K tiles (swizzled)
constexpr size_t OFF_VB    = (size_t)16 << 20;        // 16 MB V^T tiles (swizzled)
constexpr size_t OFF_HDR   = (size_t)32 << 20;        // hdr ints (below)
constexpr size_t OFF_ITEMS = OFF_HDR + 4096;          // int[8][256]
constexpr size_t OFF_L0    = OFF_HDR + 65536;         // f32[32][2048]
constexpr size_t OFF_LC    = OFF_L0 + 262144;         // f32[96][2048]
constexpr size_t OFF_PO    = OFF_LC + 786432;         // slots x 1MB
constexpr size_t PO_STRIDE = (size_t)QLEN * DH * 4;   // 1 MB
// hdr: [0..7]=queue len, [8..15]=queue counter, [16+2b]=slotbase, [17+2b]=chunks(0=unsplit)

// K tile image: [64 keys][128 d] bf16, row 256B, XOR swizzle by key.
__device__ __forceinline__ int swzK(int key, int byteoff) {
  return (key * 256 + byteoff) ^ ((key & 7) << 4);
}
// V^T tile image: [128 d][64 keys] bf16, row 128B.
__device__ __forceinline__ int swzV(int d, int byteoff) {
  return (d * 128 + byteoff) ^ (((d ^ (d >> 3)) & 7) << 4);
}

__device__ __forceinline__ void gld16(const void* g, void* l) {
  __builtin_amdgcn_global_load_lds(
      (const __attribute__((address_space(1))) void*)g,
      (__attribute__((address_space(3))) void*)l, 16, 0, 0);
}

__device__ __forceinline__ unsigned cvtpk(float lo, float hi2) {
  unsigned r;
  asm("v_cvt_pk_bf16_f32 %0, %1, %2" : "=v"(r) : "v"(lo), "v"(hi2));
  return r;
}

// ---- pre-pass: swizzled K/V tiles (zero past L) + per-XCD item queues ----
__global__ __launch_bounds__(256)
void conv_kv(const float* __restrict__ Kg, const float* __restrict__ Vg,
             const int* __restrict__ Lg, bf16* __restrict__ KbT,
             bf16* __restrict__ VbT, int* __restrict__ hdr,
             int* __restrict__ items, int budget)
{
  __shared__ int s_nt[32];
  if (blockIdx.x == 0) {
    const int t = threadIdx.x;
    if (t < 32) s_nt[t] = (Lg[t] + KVBLK - 1) / KVBLK;
    __syncthreads();
    if (t < 8) {
      int bg = budget >> 3;            // per-XCD slot budget
      if (bg > MAXSLOTS / 8) bg = MAXSLOTS / 8;
      const int base = t * bg;
      // 4 batches of this XCD group, LPT (nt desc)
      int bs[4];
      #pragma unroll
      for (int i2 = 0; i2 < 4; ++i2) bs[i2] = t + 8 * i2;
      for (int i2 = 1; i2 < 4; ++i2) {
        const int key = bs[i2];
        int j = i2 - 1;
        while (j >= 0 && (s_nt[bs[j]] < s_nt[key] ||
                          (s_nt[bs[j]] == s_nt[key] && bs[j] > key))) {
          bs[j + 1] = bs[j]; --j;
        }
        bs[j + 1] = key;
      }
      int used = 0, pos = 0;
      for (int i2 = 0; i2 < 4; ++i2) {
        const int b = bs[i2];
        const int nt = s_nt[b];
        int chunks = (nt + CHUNK - 1) / CHUNK, sp = 0;
        if (chunks > 1 && used + chunks - 1 <= bg) sp = 1;
        else chunks = 1;
        hdr[16 + 2 * b] = base + used;
        hdr[17 + 2 * b] = sp ? chunks : 0;
        for (int ci = 0; ci < chunks; ++ci) {
          const int tb = ci * CHUNK;
          int te = sp ? tb + CHUNK : nt;
          if (te > nt) te = nt;
          const int first = (ci == 0) ? 1 : 0;
          const int slot = (sp && ci > 0) ? base + used + ci - 1 : 0;
          const int enc = b | (0 << 5) | (tb << 9) | (te << 15) |
                          (sp << 21) | (first << 22) | (slot << 23);
          for (int qt = 0; qt < 16; ++qt)
            items[t * QCAP + pos++] = enc | (qt << 5);
        }
        if (sp) used += chunks - 1;
      }
      hdr[t]     = pos;   // queue length
      hdr[8 + t] = 0;     // queue counter
    }
  }

  // bulk convert: K chunks (2^20) then V chunks (2^20)
  constexpr int KCH = BATCH * NT * 64 * 16;
  constexpr int VCH = BATCH * NT * 8 * 128;
  const int stride = gridDim.x * blockDim.x;
  for (int i = blockIdx.x * blockDim.x + threadIdx.x; i < KCH + VCH; i += stride) {
    if (i < KCH) {               // (b, kt, key, i8)
      const int i8  = i & 15;
      const int key = (i >> 4) & 63;
      const int kt  = (i >> 10) & 31;
      const int b   = i >> 15;
      const int k   = kt * 64 + key;
      bf16x8 val = {};
      if (k < Lg[b]) {
        const float* src = Kg + ((size_t)b * KLEN + k) * DH + i8 * 8;
        f32x4 a = *(const f32x4*)src;
        f32x4 c = *(const f32x4*)(src + 4);
        #pragma unroll
        for (int j = 0; j < 4; ++j) { val[j] = (bf16)a[j]; val[4 + j] = (bf16)c[j]; }
      }
      *(bf16x8*)((char*)KbT + (((size_t)b * NT + kt) << 14) + swzK(key, i8 * 16)) = val;
    } else {                     // (b, kt, ko, d)
      const int j2 = i - KCH;
      const int d  = j2 & 127;
      const int ko = (j2 >> 7) & 7;
      const int kt = (j2 >> 10) & 31;
      const int b  = j2 >> 15;
      const int kb = kt * 64 + ko * 8;
      const int Lb = Lg[b];
      bf16x8 val = {};
      #pragma unroll
      for (int r = 0; r < 8; ++r) {
        float f = 0.f;
        if (kb + r < Lb) f = Vg[((size_t)b * KLEN + kb + r) * DH + d];
        val[r] = (bf16)f;
      }
      *(bf16x8*)((char*)VbT + (((size_t)b * NT + kt) << 14) + swzV(d, ko * 16)) = val;
    }
  }
}

// ---- persistent attention kernel with XCD-affine queues ----
__global__ __launch_bounds__(256, 3)
void fa_dyn(const float* __restrict__ Qg, const int* __restrict__ Lg,
            float* __restrict__ Og, const bf16* __restrict__ KbT,
            const bf16* __restrict__ VbT, const int* __restrict__ items,
            int* __restrict__ hdr, float* __restrict__ L0,
            float* __restrict__ Lc, float* __restrict__ Po)
{
  __shared__ bf16 s_k[2][KVBLK * DH];   // 32 KB, swizzled image (dbuf)
  __shared__ bf16 s_vt[KVBLK * DH];     // 16 KB, swizzled V^T image
  __shared__ int  s_enc;

  const int tid  = threadIdx.x;
  const int wave = tid >> 6;
  const int lane = tid & 63;
  const int c    = lane & 31;
  const int hi   = lane >> 5;
  const int q0   = blockIdx.x & 7;      // XCD-affine home queue
  const float SC = 0.08838834764831845f * 1.4426950408889634f; // log2e/sqrt(D)

  for (;;) {
    if (tid == 0) {
      int enc = -1;
      for (int t2 = 0; t2 < 8 && enc < 0; ++t2) {
        const int qq = (q0 + t2) & 7;
        const int len = hdr[qq];
        const int idx = atomicAdd(&hdr[8 + qq], 1);
        if (idx < len) enc = items[qq * QCAP + idx];
      }
      s_enc = enc;
    }
    __syncthreads();   // broadcast + guards LDS reuse across items
    const int enc = s_enc;
    if (enc < 0) return;

    const int b     = enc & 31;
    const int qt    = (enc >> 5) & 15;
    const int tb    = (enc >> 9) & 63;
    const int te    = (enc >> 15) & 63;
    const int sp    = (enc >> 21) & 1;
    const int first = (enc >> 22) & 1;
    const int slot  = (enc >> 23) & 127;
    const int L     = Lg[b];

    const size_t baseQ = ((size_t)b * QLEN + (size_t)qt * QBLK) * DH;
    const char* Kbase = (const char*)KbT + (((size_t)b * NT) << 14);
    const char* Vbase = (const char*)VbT + (((size_t)b * NT) << 14);

    auto stageK = [&](int buf, int kt) {
      const char* tile = Kbase + ((size_t)kt << 14);
      #pragma unroll
      for (int s2 = 0; s2 < 4; ++s2) {
        const int off = wave * 4096 + s2 * 1024;
        gld16(tile + off + lane * 16, (char*)&s_k[buf][0] + off);
      }
    };
    auto stageV = [&](int kt) {
      const char* tile = Vbase + ((size_t)kt << 14);
      #pragma unroll
      for (int s2 = 0; s2 < 4; ++s2) {
        const int off = wave * 4096 + s2 * 1024;
        gld16(tile + off + lane * 16, (char*)&s_vt[0] + off);
      }
    };

    // Q fragments pre-scaled by SC. B-frag: col = lane&31, k = 8*hi+i.
    bf16x8 qf[8];
    {
      const float* qp = Qg + baseQ + (size_t)(wave * 32 + c) * DH + hi * 8;
      #pragma unroll
      for (int dc = 0; dc < 8; ++dc) {
        f32x4 a = *(const f32x4*)(qp + dc * 16);
        f32x4 bb = *(const f32x4*)(qp + dc * 16 + 4);
        #pragma unroll
        for (int j = 0; j < 4; ++j) {
          qf[dc][j]     = (bf16)(a[j] * SC);
          qf[dc][4 + j] = (bf16)(bb[j] * SC);
        }
      }
    }

    f32x16 o[4];
    #pragma unroll
    for (int db = 0; db < 4; ++db)
      #pragma unroll
      for (int j = 0; j < 16; ++j) o[db][j] = 0.f;
    float la0 = 0.f, la1 = 0.f, la2 = 0.f, la3 = 0.f;   // tree-sum l

    stageK(0, tb);
    __syncthreads();   // prologue drain (Q loads + K(tb))

    for (int kt = tb; kt < te; ++kt) {
      const int cur   = (kt - tb) & 1;
      const bool more = (kt + 1 < te);
      stageV(kt);                       // needed at barrier #1
      if (more) stageK(cur ^ 1, kt + 1);// needed at end-of-tile

      // ---- S^T = K · Q^T (log2-prescaled) ----
      f32x16 st[2];
      __builtin_amdgcn_s_setprio(1);
      #pragma unroll
      for (int a = 0; a < 2; ++a) {
        #pragma unroll
        for (int j = 0; j < 16; ++j) st[a][j] = 0.f;
        const int key = a * 32 + c;
        #pragma unroll
        for (int dc = 0; dc < 8; ++dc) {
          bf16x8 kf = *(const bf16x8*)((const char*)&s_k[cur][0] +
                                       swzK(key, dc * 32 + hi * 16));
          st[a] = __builtin_amdgcn_mfma_f32_32x32x16_bf16(kf, qf[dc], st[a], 0, 0, 0);
        }
      }
      __builtin_amdgcn_s_setprio(0);

      // ---- fixed-m softmax: p = exp2(s), masked on boundary tile ----
      const bool partial = ((kt + 1) * KVBLK > L);
      const int k0 = kt * KVBLK;
      #pragma unroll
      for (int a = 0; a < 2; ++a)
        #pragma unroll
        for (int r = 0; r < 16; ++r) {
          float p = __builtin_amdgcn_exp2f(st[a][r]);
          if (partial) {
            const int key = k0 + a * 32 + (r & 3) + 8 * (r >> 2) + 4 * hi;
            if (key >= L) p = 0.f;
          }
          st[a][r] = p;
          if ((r & 3) == 0) la0 += p;
          else if ((r & 3) == 1) la1 += p;
          else if ((r & 3) == 2) la2 += p;
          else la3 += p;
        }

      // ---- barrier #1: V landed for all waves; K(kt+1) stays in flight ----
      if (more) { asm volatile("s_waitcnt vmcnt(4)" ::: "memory"); }
      else      { asm volatile("s_waitcnt vmcnt(0)" ::: "memory"); }
      __builtin_amdgcn_s_barrier();
      __builtin_amdgcn_sched_barrier(0);

      // ---- O += P · V; P-repack via cvt_pk + permlane32_swap ----
      __builtin_amdgcn_s_setprio(1);
      #pragma unroll
      for (int kc = 0; kc < 4; ++kc) {
        const int a = kc >> 1, g = kc & 1;
        unsigned X0 = cvtpk(st[a][8 * g + 0], st[a][8 * g + 1]);
        unsigned Y0 = cvtpk(st[a][8 * g + 4], st[a][8 * g + 5]);
        unsigned X1 = cvtpk(st[a][8 * g + 2], st[a][8 * g + 3]);
        unsigned Y1 = cvtpk(st[a][8 * g + 6], st[a][8 * g + 7]);
        asm volatile("v_permlane32_swap_b32 %0, %1" : "+v"(X0), "+v"(Y0));
        asm volatile("v_permlane32_swap_b32 %0, %1" : "+v"(X1), "+v"(Y1));
        union { unsigned u[4]; bf16x8 h; } pa;
        pa.u[0] = X0; pa.u[1] = X1; pa.u[2] = Y0; pa.u[3] = Y1;
        #pragma unroll
        for (int db = 0; db < 4; ++db) {
          const int d = db * 32 + c;
          bf16x8 vb = *(const bf16x8*)((const char*)&s_vt[0] +
                                       swzV(d, kc * 32 + hi * 16));
          o[db] = __builtin_amdgcn_mfma_f32_32x32x16_bf16(pa.h, vb, o[db], 0, 0, 0);
        }
      }
      __builtin_amdgcn_s_setprio(0);

      if (more) __syncthreads();   // PV reads done + K(kt+1) drained
    }

    // ---- epilogue ----
    const float l_acc = (la0 + la1) + (la2 + la3);
    const float l_row = l_acc + __shfl_xor(l_acc, 32);
    if (!sp) {
      float inv[16];
      #pragma unroll
      for (int j = 0; j < 16; ++j)
        inv[j] = 1.f / __shfl(l_row, (j & 3) + 8 * (j >> 2) + 4 * hi, 64);
      float* op = Og + baseQ + (size_t)(wave * 32) * DH;
      #pragma unroll
      for (int db = 0; db < 4; ++db)
        #pragma unroll
        for (int j = 0; j < 16; ++j) {
          const int row = (j & 3) + 8 * (j >> 2) + 4 * hi;
          op[(size_t)row * DH + db * 32 + c] = o[db][j] * inv[j];
        }
    } else {
      float* op = first ? Og + baseQ + (size_t)(wave * 32) * DH
                        : Po + (size_t)slot * QLEN * DH +
                          (size_t)(qt * QBLK + wave * 32) * DH;
      #pragma unroll
      for (int db = 0; db < 4; ++db)
        #pragma unroll
        for (int j = 0; j < 16; ++j) {
          const int row = (j & 3) + 8 * (j >> 2) + 4 * hi;
          op[(size_t)row * DH + db * 32 + c] = o[db][j];
        }
      float* Lp = (first ? L0 + b * QLEN : Lc + (size_t)slot * QLEN) +
                  qt * QBLK + wave * 32;
      if (hi == 0) Lp[c] = l_row;
    }
  }
}

// ---- combine: for split batches, Og = (Og + sum Po) / (L0 + sum Lc) ----
__global__ __launch_bounds__(256)
void combine(float* __restrict__ Og, const int* __restrict__ hdr,
             const float* __restrict__ L0, const float* __restrict__ Lc,
             const float* __restrict__ Po)
{
  const int total = 32 * QLEN * (DH / 4);   // (b, row, d4)
  for (int u = blockIdx.x * blockDim.x + threadIdx.x; u < total;
       u += gridDim.x * blockDim.x) {
    const int b   = u >> 16;
    const int row = (u >> 5) & 2047;
    const int d4  = u & 31;
    const int nch = hdr[17 + 2 * b];
    if (nch == 0) continue;
    const int base = hdr[16 + 2 * b];
    float l = L0[b * QLEN + row];
    const size_t og = ((size_t)b * QLEN + row) * DH + d4 * 4;
    f32x4 acc = *(const f32x4*)(Og + og);
    for (int s = 0; s < nch - 1; ++s) {
      l += Lc[(size_t)(base + s) * QLEN + row];
      f32x4 p = *(const f32x4*)(Po + (size_t)(base + s) * QLEN * DH +
                                (size_t)row * DH + d4 * 4);
      #pragma unroll
      for (int j = 0; j < 4; ++j) acc[j] += p[j];
    }
    const float inv = 1.f / l;
    #pragma unroll
    for (int j = 0; j < 4; ++j) acc[j] *= inv;
    *(f32x4*)(Og + og) = acc;
  }
}

// ---- fallback (tiny ws): synchronous static kernel (known-correct) ----
union U4f { bf16x4 h; uint2 u; };
__global__ __launch_bounds__(256)
void fa_fwd_sync(const float* __restrict__ Qg, const float* __restrict__ Kg,
                 const float* __restrict__ Vg, const int* __restrict__ Lg,
                 float* __restrict__ Og)
{
  __shared__ bf16 s_k[KVBLK * DH];
  __shared__ bf16 s_vt[DH * KVBLK];
  const int tid = threadIdx.x, wave = tid >> 6, lane = tid & 63;
  const int c = lane & 31, hi = lane >> 5;
  const int bid = blockIdx.x, batch = bid & 31, qtile = bid >> 5;
  const int L = Lg[batch], nt = (L + KVBLK - 1) / KVBLK;
  const size_t baseQ = ((size_t)batch * QLEN + (size_t)qtile * 128) * DH;
  const size_t baseKV = (size_t)batch * KLEN * DH;
  const float SC = 0.08838834764831845f * 1.4426950408889634f;
  bf16x8 qf[8];
  {
    const float* qp = Qg + baseQ + (size_t)(wave * 32 + c) * DH + hi * 8;
    #pragma unroll
    for (int dc = 0; dc < 8; ++dc) {
      f32x4 a = *(const f32x4*)(qp + dc * 16);
      f32x4 bb = *(const f32x4*)(qp + dc * 16 + 4);
      #pragma unroll
      for (int j = 0; j < 4; ++j) { qf[dc][j] = (bf16)(a[j]*SC); qf[dc][4+j] = (bf16)(bb[j]*SC); }
    }
  }
  f32x16 o[4];
  #pragma unroll
  for (int db = 0; db < 4; ++db)
    #pragma unroll
    for (int j = 0; j < 16; ++j) o[db][j] = 0.f;
  float l_acc = 0.f;
  for (int kt = 0; kt < nt; ++kt) {
    const int k0 = kt * KVBLK;
    __syncthreads();
    #pragma unroll
    for (int s = 0; s < 4; ++s) {
      const int id = tid + 256 * s, key = id >> 4, i8 = id & 15;
      bf16x8 val = {};
      if (k0 + key < L) {
        const float* src = Kg + baseKV + (size_t)(k0 + key) * DH + i8 * 8;
        f32x4 a = *(const f32x4*)src; f32x4 bb = *(const f32x4*)(src + 4);
        #pragma unroll
        for (int j = 0; j < 4; ++j) { val[j] = (bf16)a[j]; val[4+j] = (bf16)bb[j]; }
      }
      *(bf16x8*)((char*)s_k + swzK(key, i8 * 16)) = val;
    }
    {
      const int vp4 = tid >> 4, vi8 = tid & 15;
      bf16x8 rv[4];
      #pragma unroll
      for (int s = 0; s < 4; ++s) {
        bf16x8 val = {};
        if (k0 + 4 * vp4 + s < L) {
          const float* src = Vg + baseKV + (size_t)(k0 + 4 * vp4 + s) * DH + vi8 * 8;
          f32x4 a = *(const f32x4*)src; f32x4 bb = *(const f32x4*)(src + 4);
          #pragma unroll
          for (int j = 0; j < 4; ++j) { val[j] = (bf16)a[j]; val[4+j] = (bf16)bb[j]; }
        }
        rv[s] = val;
      }
      #pragma unroll
      for (int j = 0; j < 8; ++j) {
        bf16x4 w = { rv[0][j], rv[1][j], rv[2][j], rv[3][j] };
        *(bf16x4*)((char*)s_vt + swzV(vi8 * 8 + j, vp4 * 8)) = w;
      }
    }
    __syncthreads();
    f32x16 st[2];
    #pragma unroll
    for (int a = 0; a < 2; ++a) {
      #pragma unroll
      for (int j = 0; j < 16; ++j) st[a][j] = 0.f;
      const int key = a * 32 + c;
      #pragma unroll
      for (int dc = 0; dc < 8; ++dc) {
        bf16x8 kf = *(const bf16x8*)((const char*)s_k + swzK(key, dc * 32 + hi * 16));
        st[a] = __builtin_amdgcn_mfma_f32_32x32x16_bf16(kf, qf[dc], st[a], 0, 0, 0);
      }
    }
    const bool partial = (k0 + KVBLK > L);
    #pragma unroll
    for (int a = 0; a < 2; ++a)
      #pragma unroll
      for (int r = 0; r < 16; ++r) {
        float p = __builtin_amdgcn_exp2f(st[a][r]);
        if (partial) {
          const int key = k0 + a * 32 + (r & 3) + 8 * (r >> 2) + 4 * hi;
          if (key >= L) p = 0.f;
        }
        st[a][r] = p; l_acc += p;
      }
    #pragma unroll
    for (int kc = 0; kc < 4; ++kc) {
      const int a = kc >> 1, g = kc & 1;
      bf16x4 A, Bv;
      #pragma unroll
      for (int q2 = 0; q2 < 4; ++q2) { A[q2] = (bf16)st[a][q2+8*g]; Bv[q2] = (bf16)st[a][q2+8*g+4]; }
      U4f snd; snd.h = hi ? A : Bv;
      U4f rcv;
      rcv.u.x = (unsigned)__shfl_xor((int)snd.u.x, 32);
      rcv.u.y = (unsigned)__shfl_xor((int)snd.u.y, 32);
      bf16x4 loh = hi ? rcv.h : A;
      bf16x4 hih = hi ? Bv : rcv.h;
      bf16x8 pa;
      #pragma unroll
      for (int q2 = 0; q2 < 4; ++q2) { pa[q2] = loh[q2]; pa[q2+4] = hih[q2]; }
      #pragma unroll
      for (int db = 0; db < 4; ++db) {
        const int d = db * 32 + c;
        bf16x8 vb = *(const bf16x8*)((const char*)s_vt + swzV(d, kc * 32 + hi * 16));
        o[db] = __builtin_amdgcn_mfma_f32_32x32x16_bf16(pa, vb, o[db], 0, 0, 0);
      }
    }
  }
  const float l_row = l_acc + __shfl_xor(l_acc, 32);
  float inv[16];
  #pragma unroll
  for (int j = 0; j < 16; ++j)
    inv[j] = 1.f / __shfl(l_row, (j & 3) + 8 * (j >> 2) + 4 * hi, 64);
  float* op = Og + baseQ + (size_t)(wave * 32) * DH;
  #pragma unroll
  for (int db = 0; db < 4; ++db)
    #pragma unroll
    for (int j = 0; j < 16; ++j) {
      const int row = (j & 3) + 8 * (j >> 2) + 4 * hi;
      op[(size_t)row * DH + db * 32 + c] = o[db][j] * inv[j];
    }
}

extern "C" void kernel_launch(void* const* d_in, const int* in_sizes, int n_in,
                              void* d_out, int out_size, void* d_ws, size_t ws_size,
                              hipStream_t stream) {
  const float* q = (const float*)d_in[0];
  const float* k = (const float*)d_in[1];
  const float* v = (const float*)d_in[2];
  const int* lens = (const int*)d_in[3];
  float* out = (float*)d_out;

  if (ws_size >= OFF_PO) {
    char* W = (char*)d_ws;
    bf16* KbT = (bf16*)(W + OFF_KB);
    bf16* VbT = (bf16*)(W + OFF_VB);
    int*  hdr = (int*)(W + OFF_HDR);
    int*  items = (int*)(W + OFF_ITEMS);
    float* L0 = (float*)(W + OFF_L0);
    float* Lc = (float*)(W + OFF_LC);
    float* Po = (float*)(W + OFF_PO);
    int budget = (int)((ws_size - OFF_PO) / PO_STRIDE);
    if (budget > MAXSLOTS) budget = MAXSLOTS;
    hipLaunchKernelGGL(conv_kv, dim3(2048), dim3(256), 0, stream,
                       k, v, lens, KbT, VbT, hdr, items, budget);
    hipLaunchKernelGGL(fa_dyn, dim3(768), dim3(256), 0, stream,
                       q, lens, out, KbT, VbT, items, hdr, L0, Lc, Po);
    hipLaunchKernelGGL(combine, dim3(2048), dim3(256), 0, stream,
                       out, hdr, L0, Lc, Po);
  } else {
    hipLaunchKernelGGL(fa_fwd_sync, dim3(BATCH * (QLEN / 128)), dim3(256),
                       0, stream, q, k, v, lens, out);
  }
}

// Round 10
// 655.133 us; speedup vs baseline: 1.1815x; 1.1815x over previous
//
#include <hip/hip_runtime.h>

// Masked dot-product attention. INPUTS float32, OUTPUT float32.
// B=32, Q=K=2048, D=128.
// R10: R7's validated fa_dyn body (93us: __syncthreads barriers, shfl_xor
// P-exchange, pre-swizzled tiles + global_load_lds, fixed-m softmax,
// half-split items) with ONE change: XCD-affine work queues (batch%8
// affinity, home queue = blockIdx.x&7, batch-major LPT order, steal when
// empty) so each XCD's staging working set (~3MB) fits its private L2.
// R9's counted-vmcnt raw barrier reverted (compiler-inserted conservative
// drains serialized the pipeline -> 7x regression).

using bf16   = __bf16;
using bf16x4 = __attribute__((ext_vector_type(4)))  __bf16;
using bf16x8 = __attribute__((ext_vector_type(8)))  __bf16;
using f32x4  = __attribute__((ext_vector_type(4)))  float;
using f32x16 = __attribute__((ext_vector_type(16))) float;

constexpr int BATCH = 32;
constexpr int QLEN  = 2048;
constexpr int KLEN  = 2048;
constexpr int DH    = 128;
constexpr int QBLK  = 128;          // q-rows per item (4 waves x 32)
constexpr int KVBLK = 64;           // kv tile
constexpr int NT    = KLEN / KVBLK; // 32
constexpr int SPLIT_MIN_T = 14;     // split batches with >= 14 tiles (halves)
constexpr int QCAP  = 128;          // max items per XCD queue
constexpr int MAXSLOTS = 32;

// ---- workspace layout (byte offsets) ----
constexpr size_t OFF_KB    = 0;                       // 16 MB K tiles (swizzled)
constexpr size_t OFF_VB    = (size_t)16 << 20;        // 16 MB V^T tiles (swizzled)
constexpr size_t OFF_HDR   = (size_t)32 << 20;
constexpr size_t OFF_ITEMS = OFF_HDR + 4096;          // int[8][128]
constexpr size_t OFF_L0    = OFF_HDR + 65536;         // f32[32 slots][16][128]
constexpr size_t OFF_L1    = OFF_L0 + 262144;
constexpr size_t OFF_PO    = OFF_L1 + 262144;         // 32 slots x 1MB
constexpr size_t PO_STRIDE = (size_t)16 * QBLK * DH * 4;   // 1 MB
// hdr: [0..7]=queue len, [8..15]=queue counter, [16+s]=slot->batch (-1 inactive)

// K tile image: [64 keys][128 d] bf16, row 256B, XOR swizzle by key.
__device__ __forceinline__ int swzK(int key, int byteoff) {
  return (key * 256 + byteoff) ^ ((key & 7) << 4);
}
// V^T tile image: [128 d][64 keys] bf16, row 128B.
__device__ __forceinline__ int swzV(int d, int byteoff) {
  return (d * 128 + byteoff) ^ (((d ^ (d >> 3)) & 7) << 4);
}

__device__ __forceinline__ void gld16(const void* g, void* l) {
  __builtin_amdgcn_global_load_lds(
      (const __attribute__((address_space(1))) void*)g,
      (__attribute__((address_space(3))) void*)l, 16, 0, 0);
}

union U4f { bf16x4 h; uint2 u; };

// ---- pre-pass: swizzled K/V tiles (zero past L) + XCD-affine queues ----
__global__ __launch_bounds__(256)
void conv_kv(const float* __restrict__ Kg, const float* __restrict__ Vg,
             const int* __restrict__ Lg, bf16* __restrict__ KbT,
             bf16* __restrict__ VbT, int* __restrict__ hdr,
             int* __restrict__ items, int budget)
{
  __shared__ int s_nt[32];
  if (blockIdx.x == 0) {
    const int t = threadIdx.x;
    if (t < 32) s_nt[t] = (Lg[t] + KVBLK - 1) / KVBLK;
    __syncthreads();
    if (t < 8) {
      // 4 batches of this queue, LPT (nt desc)
      int bs[4];
      #pragma unroll
      for (int i2 = 0; i2 < 4; ++i2) bs[i2] = t + 8 * i2;
      for (int i2 = 1; i2 < 4; ++i2) {
        const int key = bs[i2];
        int j = i2 - 1;
        while (j >= 0 && (s_nt[bs[j]] < s_nt[key] ||
                          (s_nt[bs[j]] == s_nt[key] && bs[j] > key))) {
          bs[j + 1] = bs[j]; --j;
        }
        bs[j + 1] = key;
      }
      int pos = 0;
      for (int i2 = 0; i2 < 4; ++i2) {
        const int b    = bs[i2];
        const int nt   = s_nt[b];
        const int slot = t * 4 + i2;
        const int sp   = (nt >= SPLIT_MIN_T && slot < budget) ? 1 : 0;
        hdr[16 + slot] = sp ? b : -1;
        if (sp) {
          const int h = nt >> 1;
          const int encH = b | (0 << 9) | (h << 15) | (1 << 21) | (0 << 22) | (slot << 23);
          for (int qt = 0; qt < 16; ++qt)
            items[t * QCAP + pos++] = encH | (qt << 5);
          const int encT = b | (h << 9) | (nt << 15) | (1 << 21) | (1 << 22) | (slot << 23);
          for (int qt = 0; qt < 16; ++qt)
            items[t * QCAP + pos++] = encT | (qt << 5);
        } else {
          const int enc = b | (0 << 9) | (nt << 15);
          for (int qt = 0; qt < 16; ++qt)
            items[t * QCAP + pos++] = enc | (qt << 5);
        }
      }
      hdr[t]     = pos;   // queue length
      hdr[8 + t] = 0;     // queue counter
    }
  }

  // bulk convert: K chunks (2^20) then V chunks (2^20)
  constexpr int KCH = BATCH * NT * 64 * 16;
  constexpr int VCH = BATCH * NT * 8 * 128;
  const int stride = gridDim.x * blockDim.x;
  for (int i = blockIdx.x * blockDim.x + threadIdx.x; i < KCH + VCH; i += stride) {
    if (i < KCH) {               // (b, kt, key, i8)
      const int i8  = i & 15;
      const int key = (i >> 4) & 63;
      const int kt  = (i >> 10) & 31;
      const int b   = i >> 15;
      const int k   = kt * 64 + key;
      bf16x8 val = {};
      if (k < Lg[b]) {
        const float* src = Kg + ((size_t)b * KLEN + k) * DH + i8 * 8;
        f32x4 a = *(const f32x4*)src;
        f32x4 c = *(const f32x4*)(src + 4);
        #pragma unroll
        for (int j = 0; j < 4; ++j) { val[j] = (bf16)a[j]; val[4 + j] = (bf16)c[j]; }
      }
      *(bf16x8*)((char*)KbT + (((size_t)b * NT + kt) << 14) + swzK(key, i8 * 16)) = val;
    } else {                     // (b, kt, ko, d)
      const int j2 = i - KCH;
      const int d  = j2 & 127;
      const int ko = (j2 >> 7) & 7;
      const int kt = (j2 >> 10) & 31;
      const int b  = j2 >> 15;
      const int kb = kt * 64 + ko * 8;
      const int Lb = Lg[b];
      bf16x8 val = {};
      #pragma unroll
      for (int r = 0; r < 8; ++r) {
        float f = 0.f;
        if (kb + r < Lb) f = Vg[((size_t)b * KLEN + kb + r) * DH + d];
        val[r] = (bf16)f;
      }
      *(bf16x8*)((char*)VbT + (((size_t)b * NT + kt) << 14) + swzV(d, ko * 16)) = val;
    }
  }
}

// ---- persistent attention kernel, XCD-affine queues (R7 body) ----
__global__ __launch_bounds__(256, 3)
void fa_dyn(const float* __restrict__ Qg, const int* __restrict__ Lg,
            float* __restrict__ Og, const bf16* __restrict__ KbT,
            const bf16* __restrict__ VbT, const int* __restrict__ items,
            int* __restrict__ hdr, float* __restrict__ L0,
            float* __restrict__ L1, float* __restrict__ Po)
{
  __shared__ bf16 s_k[2][KVBLK * DH];   // 32 KB, swizzled image (dbuf)
  __shared__ bf16 s_vt[KVBLK * DH];     // 16 KB, swizzled V^T image
  __shared__ int  s_enc;

  const int tid  = threadIdx.x;
  const int wave = tid >> 6;
  const int lane = tid & 63;
  const int c    = lane & 31;
  const int hi   = lane >> 5;
  const int q0   = blockIdx.x & 7;      // XCD-affine home queue
  const float SC = 0.08838834764831845f * 1.4426950408889634f; // log2e/sqrt(D)

  for (;;) {
    if (tid == 0) {
      int enc = -1;
      for (int t2 = 0; t2 < 8 && enc < 0; ++t2) {
        const int qq  = (q0 + t2) & 7;
        const int len = hdr[qq];
        const int idx = atomicAdd(&hdr[8 + qq], 1);
        if (idx < len) enc = items[qq * QCAP + idx];
      }
      s_enc = enc;
    }
    __syncthreads();   // broadcast + guards LDS reuse across items
    const int enc = s_enc;
    if (enc < 0) return;

    const int b    = enc & 31;
    const int qt   = (enc >> 5) & 15;
    const int tb   = (enc >> 9) & 63;
    const int te   = (enc >> 15) & 63;
    const int sp   = (enc >> 21) & 1;
    const int tail = (enc >> 22) & 1;
    const int slot = (enc >> 23) & 31;
    const int L    = Lg[b];

    const size_t baseQ = ((size_t)b * QLEN + (size_t)qt * QBLK) * DH;
    const char* Kbase = (const char*)KbT + (((size_t)b * NT) << 14);
    const char* Vbase = (const char*)VbT + (((size_t)b * NT) << 14);

    auto stageK = [&](int buf, int kt) {
      const char* tile = Kbase + ((size_t)kt << 14);
      #pragma unroll
      for (int s2 = 0; s2 < 4; ++s2) {
        const int off = wave * 4096 + s2 * 1024;
        gld16(tile + off + lane * 16, (char*)&s_k[buf][0] + off);
      }
    };
    auto stageV = [&](int kt) {
      const char* tile = Vbase + ((size_t)kt << 14);
      #pragma unroll
      for (int s2 = 0; s2 < 4; ++s2) {
        const int off = wave * 4096 + s2 * 1024;
        gld16(tile + off + lane * 16, (char*)&s_vt[0] + off);
      }
    };

    // Q fragments pre-scaled by SC. B-frag: col = lane&31, k = 8*hi+i.
    bf16x8 qf[8];
    {
      const float* qp = Qg + baseQ + (size_t)(wave * 32 + c) * DH + hi * 8;
      #pragma unroll
      for (int dc = 0; dc < 8; ++dc) {
        f32x4 a = *(const f32x4*)(qp + dc * 16);
        f32x4 bb = *(const f32x4*)(qp + dc * 16 + 4);
        #pragma unroll
        for (int j = 0; j < 4; ++j) {
          qf[dc][j]     = (bf16)(a[j] * SC);
          qf[dc][4 + j] = (bf16)(bb[j] * SC);
        }
      }
    }

    f32x16 o[4];
    #pragma unroll
    for (int db = 0; db < 4; ++db)
      #pragma unroll
      for (int j = 0; j < 16; ++j) o[db][j] = 0.f;
    float l_acc = 0.f;

    stageK(0, tb);
    __syncthreads();   // prologue drain (Q loads + K(tb))

    for (int kt = tb; kt < te; ++kt) {
      const int cur   = (kt - tb) & 1;
      const bool more = (kt + 1 < te);
      stageV(kt);                       // overlaps QK^T + softmax
      if (more) stageK(cur ^ 1, kt + 1);

      // ---- S^T = K · Q^T (log2-prescaled) ----
      f32x16 st[2];
      __builtin_amdgcn_s_setprio(1);
      #pragma unroll
      for (int a = 0; a < 2; ++a) {
        #pragma unroll
        for (int j = 0; j < 16; ++j) st[a][j] = 0.f;
        const int key = a * 32 + c;
        #pragma unroll
        for (int dc = 0; dc < 8; ++dc) {
          bf16x8 kf = *(const bf16x8*)((const char*)&s_k[cur][0] +
                                       swzK(key, dc * 32 + hi * 16));
          st[a] = __builtin_amdgcn_mfma_f32_32x32x16_bf16(kf, qf[dc], st[a], 0, 0, 0);
        }
      }
      __builtin_amdgcn_s_setprio(0);

      // ---- fixed-m softmax: p = exp2(s), masked on boundary tile ----
      const bool partial = ((kt + 1) * KVBLK > L);
      const int k0 = kt * KVBLK;
      #pragma unroll
      for (int a = 0; a < 2; ++a)
        #pragma unroll
        for (int r = 0; r < 16; ++r) {
          float p = __builtin_amdgcn_exp2f(st[a][r]);
          if (partial) {
            const int key = k0 + a * 32 + (r & 3) + 8 * (r >> 2) + 4 * hi;
            if (key >= L) p = 0.f;
          }
          st[a][r] = p;
          l_acc += p;
        }

      __syncthreads();   // drains V(kt) [+K(kt+1)]; all waves' LDS ready

      // ---- O += P · V with in-register P exchange ----
      __builtin_amdgcn_s_setprio(1);
      #pragma unroll
      for (int kc = 0; kc < 4; ++kc) {
        const int a = kc >> 1, g = kc & 1;
        bf16x4 A, Bv;
        #pragma unroll
        for (int q2 = 0; q2 < 4; ++q2) {
          A[q2]  = (bf16)st[a][q2 + 8 * g];
          Bv[q2] = (bf16)st[a][q2 + 8 * g + 4];
        }
        U4f snd; snd.h = hi ? A : Bv;
        U4f rcv;
        rcv.u.x = (unsigned)__shfl_xor((int)snd.u.x, 32);
        rcv.u.y = (unsigned)__shfl_xor((int)snd.u.y, 32);
        bf16x4 loh = hi ? rcv.h : A;
        bf16x4 hih = hi ? Bv    : rcv.h;
        bf16x8 pa;
        #pragma unroll
        for (int q2 = 0; q2 < 4; ++q2) { pa[q2] = loh[q2]; pa[q2 + 4] = hih[q2]; }
        #pragma unroll
        for (int db = 0; db < 4; ++db) {
          const int d = db * 32 + c;
          bf16x8 vb = *(const bf16x8*)((const char*)&s_vt[0] +
                                       swzV(d, kc * 32 + hi * 16));
          o[db] = __builtin_amdgcn_mfma_f32_32x32x16_bf16(pa, vb, o[db], 0, 0, 0);
        }
      }
      __builtin_amdgcn_s_setprio(0);

      if (more) __syncthreads();   // PV reads done before next stage lands
    }

    // ---- epilogue ----
    const float l_row = l_acc + __shfl_xor(l_acc, 32);
    if (!sp) {
      float inv[16];
      #pragma unroll
      for (int j = 0; j < 16; ++j)
        inv[j] = 1.f / __shfl(l_row, (j & 3) + 8 * (j >> 2) + 4 * hi, 64);
      float* op = Og + baseQ + (size_t)(wave * 32) * DH;
      #pragma unroll
      for (int db = 0; db < 4; ++db)
        #pragma unroll
        for (int j = 0; j < 16; ++j) {
          const int row = (j & 3) + 8 * (j >> 2) + 4 * hi;
          op[(size_t)row * DH + db * 32 + c] = o[db][j] * inv[j];
        }
    } else {
      float* op = tail ? Po + (size_t)slot * (PO_STRIDE / 4) +
                         (size_t)(qt * QBLK + wave * 32) * DH
                       : Og + baseQ + (size_t)(wave * 32) * DH;
      #pragma unroll
      for (int db = 0; db < 4; ++db)
        #pragma unroll
        for (int j = 0; j < 16; ++j) {
          const int row = (j & 3) + 8 * (j >> 2) + 4 * hi;
          op[(size_t)row * DH + db * 32 + c] = o[db][j];
        }
      float* Lp = (tail ? L1 : L0) + (slot * 16 + qt) * 128 + wave * 32;
      if (hi == 0) Lp[c] = l_row;
    }
  }
}

// ---- combine split partials: Og = (Og + Po) / (l0 + l1) ----
__global__ __launch_bounds__(256)
void combine(float* __restrict__ Og, const int* __restrict__ hdr,
             const float* __restrict__ L0, const float* __restrict__ L1,
             const float* __restrict__ Po)
{
  const int total = 32 << 16;   // (s, q, row, d4) in f32x4 units
  for (int u = blockIdx.x * blockDim.x + threadIdx.x; u < total;
       u += gridDim.x * blockDim.x) {
    const int s = u >> 16;
    const int b = hdr[16 + s];
    if (b < 0) continue;
    const int q   = (u >> 12) & 15;
    const int row = (u >> 5) & 127;
    const int d4  = u & 31;
    const int li  = (s * 16 + q) * 128 + row;
    const float inv = 1.f / (L0[li] + L1[li]);
    const size_t og = ((size_t)b * QLEN + q * QBLK + row) * DH + d4 * 4;
    const size_t po = (size_t)s * (PO_STRIDE / 4) +
                      (size_t)(q * QBLK + row) * DH + d4 * 4;
    f32x4 a = *(const f32x4*)(Og + og);
    f32x4 p = *(const f32x4*)(Po + po);
    #pragma unroll
    for (int j = 0; j < 4; ++j) a[j] = (a[j] + p[j]) * inv;
    *(f32x4*)(Og + og) = a;
  }
}

// ---- fallback (tiny ws): synchronous static kernel (known-correct) ----
__global__ __launch_bounds__(256)
void fa_fwd_sync(const float* __restrict__ Qg, const float* __restrict__ Kg,
                 const float* __restrict__ Vg, const int* __restrict__ Lg,
                 float* __restrict__ Og)
{
  __shared__ bf16 s_k[KVBLK * DH];
  __shared__ bf16 s_vt[DH * KVBLK];
  const int tid = threadIdx.x, wave = tid >> 6, lane = tid & 63;
  const int c = lane & 31, hi = lane >> 5;
  const int bid = blockIdx.x, batch = bid & 31, qtile = bid >> 5;
  const int L = Lg[batch], nt = (L + KVBLK - 1) / KVBLK;
  const size_t baseQ = ((size_t)batch * QLEN + (size_t)qtile * 128) * DH;
  const size_t baseKV = (size_t)batch * KLEN * DH;
  const float SC = 0.08838834764831845f * 1.4426950408889634f;
  bf16x8 qf[8];
  {
    const float* qp = Qg + baseQ + (size_t)(wave * 32 + c) * DH + hi * 8;
    #pragma unroll
    for (int dc = 0; dc < 8; ++dc) {
      f32x4 a = *(const f32x4*)(qp + dc * 16);
      f32x4 bb = *(const f32x4*)(qp + dc * 16 + 4);
      #pragma unroll
      for (int j = 0; j < 4; ++j) { qf[dc][j] = (bf16)(a[j]*SC); qf[dc][4+j] = (bf16)(bb[j]*SC); }
    }
  }
  f32x16 o[4];
  #pragma unroll
  for (int db = 0; db < 4; ++db)
    #pragma unroll
    for (int j = 0; j < 16; ++j) o[db][j] = 0.f;
  float l_acc = 0.f;
  for (int kt = 0; kt < nt; ++kt) {
    const int k0 = kt * KVBLK;
    __syncthreads();
    #pragma unroll
    for (int s = 0; s < 4; ++s) {
      const int id = tid + 256 * s, key = id >> 4, i8 = id & 15;
      bf16x8 val = {};
      if (k0 + key < L) {
        const float* src = Kg + baseKV + (size_t)(k0 + key) * DH + i8 * 8;
        f32x4 a = *(const f32x4*)src; f32x4 bb = *(const f32x4*)(src + 4);
        #pragma unroll
        for (int j = 0; j < 4; ++j) { val[j] = (bf16)a[j]; val[4+j] = (bf16)bb[j]; }
      }
      *(bf16x8*)((char*)s_k + swzK(key, i8 * 16)) = val;
    }
    {
      const int vp4 = tid >> 4, vi8 = tid & 15;
      bf16x8 rv[4];
      #pragma unroll
      for (int s = 0; s < 4; ++s) {
        bf16x8 val = {};
        if (k0 + 4 * vp4 + s < L) {
          const float* src = Vg + baseKV + (size_t)(k0 + 4 * vp4 + s) * DH + vi8 * 8;
          f32x4 a = *(const f32x4*)src; f32x4 bb = *(const f32x4*)(src + 4);
          #pragma unroll
          for (int j = 0; j < 4; ++j) { val[j] = (bf16)a[j]; val[4+j] = (bf16)bb[j]; }
        }
        rv[s] = val;
      }
      #pragma unroll
      for (int j = 0; j < 8; ++j) {
        bf16x4 w = { rv[0][j], rv[1][j], rv[2][j], rv[3][j] };
        *(bf16x4*)((char*)s_vt + swzV(vi8 * 8 + j, vp4 * 8)) = w;
      }
    }
    __syncthreads();
    f32x16 st[2];
    #pragma unroll
    for (int a = 0; a < 2; ++a) {
      #pragma unroll
      for (int j = 0; j < 16; ++j) st[a][j] = 0.f;
      const int key = a * 32 + c;
      #pragma unroll
      for (int dc = 0; dc < 8; ++dc) {
        bf16x8 kf = *(const bf16x8*)((const char*)s_k + swzK(key, dc * 32 + hi * 16));
        st[a] = __builtin_amdgcn_mfma_f32_32x32x16_bf16(kf, qf[dc], st[a], 0, 0, 0);
      }
    }
    const bool partial = (k0 + KVBLK > L);
    #pragma unroll
    for (int a = 0; a < 2; ++a)
      #pragma unroll
      for (int r = 0; r < 16; ++r) {
        float p = __builtin_amdgcn_exp2f(st[a][r]);
        if (partial) {
          const int key = k0 + a * 32 + (r & 3) + 8 * (r >> 2) + 4 * hi;
          if (key >= L) p = 0.f;
        }
        st[a][r] = p; l_acc += p;
      }
    #pragma unroll
    for (int kc = 0; kc < 4; ++kc) {
      const int a = kc >> 1, g = kc & 1;
      bf16x4 A, Bv;
      #pragma unroll
      for (int q2 = 0; q2 < 4; ++q2) { A[q2] = (bf16)st[a][q2+8*g]; Bv[q2] = (bf16)st[a][q2+8*g+4]; }
      U4f snd; snd.h = hi ? A : Bv;
      U4f rcv;
      rcv.u.x = (unsigned)__shfl_xor((int)snd.u.x, 32);
      rcv.u.y = (unsigned)__shfl_xor((int)snd.u.y, 32);
      bf16x4 loh = hi ? rcv.h : A;
      bf16x4 hih = hi ? Bv : rcv.h;
      bf16x8 pa;
      #pragma unroll
      for (int q2 = 0; q2 < 4; ++q2) { pa[q2] = loh[q2]; pa[q2+4] = hih[q2]; }
      #pragma unroll
      for (int db = 0; db < 4; ++db) {
        const int d = db * 32 + c;
        bf16x8 vb = *(const bf16x8*)((const char*)s_vt + swzV(d, kc * 32 + hi * 16));
        o[db] = __builtin_amdgcn_mfma_f32_32x32x16_bf16(pa, vb, o[db], 0, 0, 0);
      }
    }
  }
  const float l_row = l_acc + __shfl_xor(l_acc, 32);
  float inv[16];
  #pragma unroll
  for (int j = 0; j < 16; ++j)
    inv[j] = 1.f / __shfl(l_row, (j & 3) + 8 * (j >> 2) + 4 * hi, 64);
  float* op = Og + baseQ + (size_t)(wave * 32) * DH;
  #pragma unroll
  for (int db = 0; db < 4; ++db)
    #pragma unroll
    for (int j = 0; j < 16; ++j) {
      const int row = (j & 3) + 8 * (j >> 2) + 4 * hi;
      op[(size_t)row * DH + db * 32 + c] = o[db][j] * inv[j];
    }
}

extern "C" void kernel_launch(void* const* d_in, const int* in_sizes, int n_in,
                              void* d_out, int out_size, void* d_ws, size_t ws_size,
                              hipStream_t stream) {
  const float* q = (const float*)d_in[0];
  const float* k = (const float*)d_in[1];
  const float* v = (const float*)d_in[2];
  const int* lens = (const int*)d_in[3];
  float* out = (float*)d_out;

  if (ws_size >= OFF_PO) {
    char* W = (char*)d_ws;
    bf16* KbT = (bf16*)(W + OFF_KB);
    bf16* VbT = (bf16*)(W + OFF_VB);
    int*  hdr = (int*)(W + OFF_HDR);
    int*  items = (int*)(W + OFF_ITEMS);
    float* L0 = (float*)(W + OFF_L0);
    float* L1 = (float*)(W + OFF_L1);
    float* Po = (float*)(W + OFF_PO);
    int budget = (int)((ws_size - OFF_PO) / PO_STRIDE);
    if (budget > MAXSLOTS) budget = MAXSLOTS;
    hipLaunchKernelGGL(conv_kv, dim3(2048), dim3(256), 0, stream,
                       k, v, lens, KbT, VbT, hdr, items, budget);
    hipLaunchKernelGGL(fa_dyn, dim3(768), dim3(256), 0, stream,
                       q, lens, out, KbT, VbT, items, hdr, L0, L1, Po);
    hipLaunchKernelGGL(combine, dim3(1024), dim3(256), 0, stream,
                       out, hdr, L0, L1, Po);
  } else {
    hipLaunchKernelGGL(fa_fwd_sync, dim3(BATCH * (QLEN / 128)), dim3(256),
                       0, stream, q, k, v, lens, out);
  }
}

// Round 11
// 112.527 us; speedup vs baseline: 6.8786x; 5.8220x over previous
//
#include <hip/hip_runtime.h>

// Masked dot-product attention. INPUTS float32, OUTPUT float32.
// B=32, Q=K=2048, D=128.
// R11: re-anchor on R7 (best verified attention kernel: fa_dyn 93us).
// Identical to R7 except conv_kv grid 4096 and combine grid 1024 (both
// grid-stride, safe). R8/R9/R10 structural changes all regressed and are
// reverted: 8-wave+lb(512,6) spilled accumulators; counted-vmcnt raw
// barrier triggered conservative compiler drains; XCD-affine queues
// caused a 6.8x uniform slowdown despite better L2 hit-rate.

using bf16   = __bf16;
using bf16x4 = __attribute__((ext_vector_type(4)))  __bf16;
using bf16x8 = __attribute__((ext_vector_type(8)))  __bf16;
using f32x4  = __attribute__((ext_vector_type(4)))  float;
using f32x16 = __attribute__((ext_vector_type(16))) float;

constexpr int BATCH = 32;
constexpr int QLEN  = 2048;
constexpr int KLEN  = 2048;
constexpr int DH    = 128;
constexpr int QBLK  = 128;     // q-rows per item (4 waves x 32)
constexpr int KVBLK = 64;      // kv tile
constexpr int NT    = KLEN / KVBLK;   // 32
constexpr int SPLIT_MIN_T = 14;       // split batches with >= 14 tiles

// ---- workspace layout (byte offsets) ----
constexpr size_t OFF_KB    = 0;                        // 16 MB K tiles
constexpr size_t OFF_VB    = (size_t)16 << 20;         // 16 MB V^T tiles
constexpr size_t OFF_HDR   = (size_t)32 << 20;         // ints: [0]=n_items [1]=counter [2]=nsplit [8+s]=batch(slot)
constexpr size_t OFF_ITEMS = OFF_HDR + 4096;           // int[1024]
constexpr size_t OFF_L0    = OFF_HDR + 32768;          // f32[32][16][128]
constexpr size_t OFF_L1    = OFF_L0 + ((size_t)256 << 10);
constexpr size_t OFF_PO    = OFF_L1 + ((size_t)256 << 10);
constexpr size_t PO_STRIDE = (size_t)1 << 20;          // f32[16][128][128] per slot

union U4f { bf16x4 h; uint2 u; };

// K tile image: [64 keys][128 d] bf16, row 256B, XOR swizzle by key.
__device__ __forceinline__ int swzK(int key, int byteoff) {
  return (key * 256 + byteoff) ^ ((key & 7) << 4);
}
// V^T tile image: [128 d][64 keys] bf16, row 128B.
__device__ __forceinline__ int swzV(int d, int byteoff) {
  return (d * 128 + byteoff) ^ (((d ^ (d >> 3)) & 7) << 4);
}

__device__ __forceinline__ void gld16(const void* g, void* l) {
  __builtin_amdgcn_global_load_lds(
      (const __attribute__((address_space(1))) void*)g,
      (__attribute__((address_space(3))) void*)l, 16, 0, 0);
}

// ---- pre-pass: build swizzled K/V tiles (zero past L) + item plan ----
__global__ __launch_bounds__(256)
void conv_kv(const float* __restrict__ Kg, const float* __restrict__ Vg,
             const int* __restrict__ Lg, bf16* __restrict__ KbT,
             bf16* __restrict__ VbT, int* __restrict__ hdr,
             int* __restrict__ items, int budget)
{
  __shared__ int sh_nt[32], sh_sp[32], sh_rk[32], sh_len[64];
  if (blockIdx.x == 0) {
    const int t = threadIdx.x;
    if (t < 32) {
      const int nt = (Lg[t] + KVBLK - 1) / KVBLK;
      int rank = 0;
      for (int j = 0; j < 32; ++j) {
        const int ntj = (Lg[j] + KVBLK - 1) / KVBLK;
        rank += (ntj > nt) || (ntj == nt && j < t);
      }
      const int sp = (nt >= SPLIT_MIN_T && rank < budget) ? 1 : 0;
      sh_nt[t] = nt; sh_sp[t] = sp; sh_rk[t] = rank;
      if (sp) hdr[8 + rank] = t;
    }
    __syncthreads();
    if (t < 64) {
      const int b = t >> 1, tl = t & 1;
      const int nt = sh_nt[b], sp = sh_sp[b];
      int tb, te;
      if (sp) { const int h = nt >> 1; tb = tl ? h : 0; te = tl ? nt : h; }
      else    { tb = 0; te = tl ? 0 : nt; }
      sh_len[t] = te - tb;
    }
    __syncthreads();
    if (t < 64) {
      const int len = sh_len[t];
      if (len > 0) {
        int r = 0;   // LPT rank among nonempty chunks (len desc)
        for (int j = 0; j < 64; ++j)
          r += (sh_len[j] > len) || (sh_len[j] == len && j < t);
        const int b = t >> 1, tl = t & 1;
        const int nt = sh_nt[b], sp = sh_sp[b];
        int tb = 0, te = nt;
        if (sp) { const int h = nt >> 1; tb = tl ? h : 0; te = tl ? nt : h; }
        const int slot = sp ? sh_rk[b] : 0;
        const int tailf = sp & tl;
        #pragma unroll
        for (int qq = 0; qq < 16; ++qq)
          items[r * 16 + qq] =
              b | (qq << 5) | (tb << 9) | (te << 15) | (sp << 21) |
              (tailf << 22) | (slot << 23);
      }
    }
    if (threadIdx.x == 0) {
      int ns = 0;
      for (int j = 0; j < 32; ++j) ns += sh_sp[j];
      hdr[0] = (32 + ns) * 16;   // n_items
      hdr[1] = 0;                // counter
      hdr[2] = ns;               // nsplit
    }
  }

  // bulk convert: K chunks (2^20) then V chunks (2^20)
  constexpr int KCH = BATCH * NT * 64 * 16;
  constexpr int VCH = BATCH * NT * 8 * 128;
  const int stride = gridDim.x * blockDim.x;
  for (int i = blockIdx.x * blockDim.x + threadIdx.x; i < KCH + VCH; i += stride) {
    if (i < KCH) {               // (b, kt, key, i8)
      const int i8  = i & 15;
      const int key = (i >> 4) & 63;
      const int kt  = (i >> 10) & 31;
      const int b   = i >> 15;
      const int k   = kt * 64 + key;
      bf16x8 val = {};
      if (k < Lg[b]) {
        const float* src = Kg + ((size_t)b * KLEN + k) * DH + i8 * 8;
        f32x4 a = *(const f32x4*)src;
        f32x4 c = *(const f32x4*)(src + 4);
        #pragma unroll
        for (int j = 0; j < 4; ++j) { val[j] = (bf16)a[j]; val[4 + j] = (bf16)c[j]; }
      }
      *(bf16x8*)((char*)KbT + (((size_t)b * NT + kt) << 14) + swzK(key, i8 * 16)) = val;
    } else {                     // (b, kt, ko, d)
      const int j2 = i - KCH;
      const int d  = j2 & 127;
      const int ko = (j2 >> 7) & 7;
      const int kt = (j2 >> 10) & 31;
      const int b  = j2 >> 15;
      const int kb = kt * 64 + ko * 8;
      const int Lb = Lg[b];
      bf16x8 val = {};
      #pragma unroll
      for (int r = 0; r < 8; ++r) {
        float f = 0.f;
        if (kb + r < Lb) f = Vg[((size_t)b * KLEN + kb + r) * DH + d];
        val[r] = (bf16)f;
      }
      *(bf16x8*)((char*)VbT + (((size_t)b * NT + kt) << 14) + swzV(d, ko * 16)) = val;
    }
  }
}

// ---- persistent dynamic-queue attention kernel (R7 body, verified 93us) ----
__global__ __launch_bounds__(256, 3)
void fa_dyn(const float* __restrict__ Qg, const int* __restrict__ Lg,
            float* __restrict__ Og, const bf16* __restrict__ KbT,
            const bf16* __restrict__ VbT, const int* __restrict__ items,
            int* __restrict__ hdr, float* __restrict__ L0,
            float* __restrict__ L1, float* __restrict__ Po)
{
  __shared__ bf16 s_k[2][KVBLK * DH];   // 32 KB, swizzled image (dbuf)
  __shared__ bf16 s_vt[KVBLK * DH];     // 16 KB, swizzled V^T image
  __shared__ int  s_item;

  const int tid  = threadIdx.x;
  const int wave = tid >> 6;
  const int lane = tid & 63;
  const int c    = lane & 31;
  const int hi   = lane >> 5;
  const float SC = 0.08838834764831845f * 1.4426950408889634f; // log2e/sqrt(D)

  const int n_items = hdr[0];

  for (;;) {
    if (tid == 0) s_item = atomicAdd(&hdr[1], 1);
    __syncthreads();
    const int it = s_item;
    if (it >= n_items) return;
    const int enc  = items[it];
    const int b    = enc & 31;
    const int qt   = (enc >> 5) & 15;
    const int tb   = (enc >> 9) & 63;
    const int te   = (enc >> 15) & 63;
    const int sp   = (enc >> 21) & 1;
    const int tail = (enc >> 22) & 1;
    const int slot = (enc >> 23) & 31;
    const int L    = Lg[b];

    const size_t baseQ = ((size_t)b * QLEN + (size_t)qt * QBLK) * DH;
    const char* Kbase = (const char*)KbT + (((size_t)b * NT) << 14);
    const char* Vbase = (const char*)VbT + (((size_t)b * NT) << 14);

    auto stageK = [&](int buf, int kt) {
      const char* tile = Kbase + ((size_t)kt << 14);
      #pragma unroll
      for (int s2 = 0; s2 < 4; ++s2) {
        const int off = wave * 4096 + s2 * 1024;
        gld16(tile + off + lane * 16, (char*)&s_k[buf][0] + off);
      }
    };
    auto stageV = [&](int kt) {
      const char* tile = Vbase + ((size_t)kt << 14);
      #pragma unroll
      for (int s2 = 0; s2 < 4; ++s2) {
        const int off = wave * 4096 + s2 * 1024;
        gld16(tile + off + lane * 16, (char*)&s_vt[0] + off);
      }
    };

    // Q fragments pre-scaled by SC. B-frag: col = lane&31, k = 8*hi+i.
    bf16x8 qf[8];
    {
      const float* qp = Qg + baseQ + (size_t)(wave * 32 + c) * DH + hi * 8;
      #pragma unroll
      for (int dc = 0; dc < 8; ++dc) {
        f32x4 a = *(const f32x4*)(qp + dc * 16);
        f32x4 bb = *(const f32x4*)(qp + dc * 16 + 4);
        #pragma unroll
        for (int j = 0; j < 4; ++j) {
          qf[dc][j]     = (bf16)(a[j] * SC);
          qf[dc][4 + j] = (bf16)(bb[j] * SC);
        }
      }
    }

    f32x16 o[4];
    #pragma unroll
    for (int db = 0; db < 4; ++db)
      #pragma unroll
      for (int j = 0; j < 16; ++j) o[db][j] = 0.f;
    float l_acc = 0.f;

    stageK(0, tb);
    __syncthreads();   // prologue drain (Q loads + K(tb))

    for (int kt = tb; kt < te; ++kt) {
      const int cur   = (kt - tb) & 1;
      const bool more = (kt + 1 < te);
      stageV(kt);                       // overlaps QK^T + softmax
      if (more) stageK(cur ^ 1, kt + 1);

      // ---- S^T = K · Q^T (log2-prescaled) ----
      f32x16 st[2];
      __builtin_amdgcn_s_setprio(1);
      #pragma unroll
      for (int a = 0; a < 2; ++a) {
        #pragma unroll
        for (int j = 0; j < 16; ++j) st[a][j] = 0.f;
        const int key = a * 32 + c;
        #pragma unroll
        for (int dc = 0; dc < 8; ++dc) {
          bf16x8 kf = *(const bf16x8*)((const char*)&s_k[cur][0] +
                                       swzK(key, dc * 32 + hi * 16));
          st[a] = __builtin_amdgcn_mfma_f32_32x32x16_bf16(kf, qf[dc], st[a], 0, 0, 0);
        }
      }
      __builtin_amdgcn_s_setprio(0);

      // ---- fixed-m softmax: p = exp2(s), masked past L ----
      const bool partial = ((kt + 1) * KVBLK > L);
      const int k0 = kt * KVBLK;
      #pragma unroll
      for (int a = 0; a < 2; ++a)
        #pragma unroll
        for (int r = 0; r < 16; ++r) {
          float p = __builtin_amdgcn_exp2f(st[a][r]);
          if (partial) {
            const int key = k0 + a * 32 + (r & 3) + 8 * (r >> 2) + 4 * hi;
            if (key >= L) p = 0.f;
          }
          st[a][r] = p;
          l_acc += p;
        }

      __syncthreads();   // drains V(kt) [+K(kt+1)]; all waves' LDS ready

      // ---- O += P · V with in-register P exchange ----
      __builtin_amdgcn_s_setprio(1);
      #pragma unroll
      for (int kc = 0; kc < 4; ++kc) {
        const int a = kc >> 1, g = kc & 1;
        bf16x4 A, Bv;
        #pragma unroll
        for (int q2 = 0; q2 < 4; ++q2) {
          A[q2]  = (bf16)st[a][q2 + 8 * g];
          Bv[q2] = (bf16)st[a][q2 + 8 * g + 4];
        }
        U4f snd; snd.h = hi ? A : Bv;
        U4f rcv;
        rcv.u.x = (unsigned)__shfl_xor((int)snd.u.x, 32);
        rcv.u.y = (unsigned)__shfl_xor((int)snd.u.y, 32);
        bf16x4 loh = hi ? rcv.h : A;
        bf16x4 hih = hi ? Bv    : rcv.h;
        bf16x8 pa;
        #pragma unroll
        for (int q2 = 0; q2 < 4; ++q2) { pa[q2] = loh[q2]; pa[q2 + 4] = hih[q2]; }
        #pragma unroll
        for (int db = 0; db < 4; ++db) {
          const int d = db * 32 + c;
          bf16x8 vb = *(const bf16x8*)((const char*)&s_vt[0] +
                                       swzV(d, kc * 32 + hi * 16));
          o[db] = __builtin_amdgcn_mfma_f32_32x32x16_bf16(pa, vb, o[db], 0, 0, 0);
        }
      }
      __builtin_amdgcn_s_setprio(0);

      if (more) __syncthreads();   // PV reads done before next stage lands
    }

    // ---- epilogue ----
    const float l_row = l_acc + __shfl_xor(l_acc, 32);
    if (!sp) {
      float inv[16];
      #pragma unroll
      for (int j = 0; j < 16; ++j)
        inv[j] = 1.f / __shfl(l_row, (j & 3) + 8 * (j >> 2) + 4 * hi, 64);
      float* op = Og + baseQ + (size_t)(wave * 32) * DH;
      #pragma unroll
      for (int db = 0; db < 4; ++db)
        #pragma unroll
        for (int j = 0; j < 16; ++j) {
          const int row = (j & 3) + 8 * (j >> 2) + 4 * hi;
          op[(size_t)row * DH + db * 32 + c] = o[db][j] * inv[j];
        }
    } else {
      float* op = tail ? Po + ((size_t)(slot * 16 + qt) * 128 + wave * 32) * DH
                       : Og + baseQ + (size_t)(wave * 32) * DH;
      #pragma unroll
      for (int db = 0; db < 4; ++db)
        #pragma unroll
        for (int j = 0; j < 16; ++j) {
          const int row = (j & 3) + 8 * (j >> 2) + 4 * hi;
          op[(size_t)row * DH + db * 32 + c] = o[db][j];
        }
      float* Lp = (tail ? L1 : L0) + (slot * 16 + qt) * 128 + wave * 32;
      if (hi == 0) Lp[c] = l_row;
    }
  }
}

// ---- combine split partials: Og = (Og + Po) / (l0 + l1) ----
__global__ __launch_bounds__(256)
void combine(float* __restrict__ Og, const int* __restrict__ hdr,
             const float* __restrict__ L0, const float* __restrict__ L1,
             const float* __restrict__ Po)
{
  const int nsplit = hdr[2];
  const int total = nsplit << 16;   // (s, q, row, d4) in f32x4 units
  for (int u = blockIdx.x * blockDim.x + threadIdx.x; u < total;
       u += gridDim.x * blockDim.x) {
    const int s   = u >> 16;
    const int q   = (u >> 12) & 15;
    const int row = (u >> 5) & 127;
    const int d4  = u & 31;
    const int b   = hdr[8 + s];
    const int li  = (s * 16 + q) * 128 + row;
    const float inv = 1.f / (L0[li] + L1[li]);
    const size_t og = ((size_t)b * QLEN + q * 128 + row) * DH + d4 * 4;
    const size_t po = ((size_t)(s * 16 + q) * 128 + row) * DH + d4 * 4;
    f32x4 a = *(const f32x4*)(Og + og);
    f32x4 p = *(const f32x4*)(Po + po);
    #pragma unroll
    for (int j = 0; j < 4; ++j) a[j] = (a[j] + p[j]) * inv;
    *(f32x4*)(Og + og) = a;
  }
}

// ---- fallback (tiny ws): synchronous static kernel (known-correct) ----
__global__ __launch_bounds__(256)
void fa_fwd_sync(const float* __restrict__ Qg, const float* __restrict__ Kg,
                 const float* __restrict__ Vg, const int* __restrict__ Lg,
                 float* __restrict__ Og)
{
  __shared__ bf16 s_k[KVBLK * DH];
  __shared__ bf16 s_vt[DH * KVBLK];
  const int tid = threadIdx.x, wave = tid >> 6, lane = tid & 63;
  const int c = lane & 31, hi = lane >> 5;
  const int bid = blockIdx.x, batch = bid & 31, qtile = bid >> 5;
  const int L = Lg[batch], nt = (L + KVBLK - 1) / KVBLK;
  const size_t baseQ = ((size_t)batch * QLEN + (size_t)qtile * 128) * DH;
  const size_t baseKV = (size_t)batch * KLEN * DH;
  const float SC = 0.08838834764831845f * 1.4426950408889634f;
  bf16x8 qf[8];
  {
    const float* qp = Qg + baseQ + (size_t)(wave * 32 + c) * DH + hi * 8;
    #pragma unroll
    for (int dc = 0; dc < 8; ++dc) {
      f32x4 a = *(const f32x4*)(qp + dc * 16);
      f32x4 bb = *(const f32x4*)(qp + dc * 16 + 4);
      #pragma unroll
      for (int j = 0; j < 4; ++j) { qf[dc][j] = (bf16)(a[j]*SC); qf[dc][4+j] = (bf16)(bb[j]*SC); }
    }
  }
  f32x16 o[4];
  #pragma unroll
  for (int db = 0; db < 4; ++db)
    #pragma unroll
    for (int j = 0; j < 16; ++j) o[db][j] = 0.f;
  float l_acc = 0.f;
  for (int kt = 0; kt < nt; ++kt) {
    const int k0 = kt * KVBLK;
    __syncthreads();
    #pragma unroll
    for (int s = 0; s < 4; ++s) {
      const int id = tid + 256 * s, key = id >> 4, i8 = id & 15;
      bf16x8 val = {};
      if (k0 + key < L) {
        const float* src = Kg + baseKV + (size_t)(k0 + key) * DH + i8 * 8;
        f32x4 a = *(const f32x4*)src; f32x4 bb = *(const f32x4*)(src + 4);
        #pragma unroll
        for (int j = 0; j < 4; ++j) { val[j] = (bf16)a[j]; val[4+j] = (bf16)bb[j]; }
      }
      *(bf16x8*)((char*)s_k + swzK(key, i8 * 16)) = val;
    }
    {
      const int vp4 = tid >> 4, vi8 = tid & 15;
      bf16x8 rv[4];
      #pragma unroll
      for (int s = 0; s < 4; ++s) {
        bf16x8 val = {};
        if (k0 + 4 * vp4 + s < L) {
          const float* src = Vg + baseKV + (size_t)(k0 + 4 * vp4 + s) * DH + vi8 * 8;
          f32x4 a = *(const f32x4*)src; f32x4 bb = *(const f32x4*)(src + 4);
          #pragma unroll
          for (int j = 0; j < 4; ++j) { val[j] = (bf16)a[j]; val[4+j] = (bf16)bb[j]; }
        }
        rv[s] = val;
      }
      #pragma unroll
      for (int j = 0; j < 8; ++j) {
        bf16x4 w = { rv[0][j], rv[1][j], rv[2][j], rv[3][j] };
        *(bf16x4*)((char*)s_vt + swzV(vi8 * 8 + j, vp4 * 8)) = w;
      }
    }
    __syncthreads();
    f32x16 st[2];
    #pragma unroll
    for (int a = 0; a < 2; ++a) {
      #pragma unroll
      for (int j = 0; j < 16; ++j) st[a][j] = 0.f;
      const int key = a * 32 + c;
      #pragma unroll
      for (int dc = 0; dc < 8; ++dc) {
        bf16x8 kf = *(const bf16x8*)((const char*)s_k + swzK(key, dc * 32 + hi * 16));
        st[a] = __builtin_amdgcn_mfma_f32_32x32x16_bf16(kf, qf[dc], st[a], 0, 0, 0);
      }
    }
    const bool partial = (k0 + KVBLK > L);
    #pragma unroll
    for (int a = 0; a < 2; ++a)
      #pragma unroll
      for (int r = 0; r < 16; ++r) {
        float p = __builtin_amdgcn_exp2f(st[a][r]);
        if (partial) {
          const int key = k0 + a * 32 + (r & 3) + 8 * (r >> 2) + 4 * hi;
          if (key >= L) p = 0.f;
        }
        st[a][r] = p; l_acc += p;
      }
    #pragma unroll
    for (int kc = 0; kc < 4; ++kc) {
      const int a = kc >> 1, g = kc & 1;
      bf16x4 A, Bv;
      #pragma unroll
      for (int q2 = 0; q2 < 4; ++q2) { A[q2] = (bf16)st[a][q2+8*g]; Bv[q2] = (bf16)st[a][q2+8*g+4]; }
      U4f snd; snd.h = hi ? A : Bv;
      U4f rcv;
      rcv.u.x = (unsigned)__shfl_xor((int)snd.u.x, 32);
      rcv.u.y = (unsigned)__shfl_xor((int)snd.u.y, 32);
      bf16x4 loh = hi ? rcv.h : A;
      bf16x4 hih = hi ? Bv : rcv.h;
      bf16x8 pa;
      #pragma unroll
      for (int q2 = 0; q2 < 4; ++q2) { pa[q2] = loh[q2]; pa[q2+4] = hih[q2]; }
      #pragma unroll
      for (int db = 0; db < 4; ++db) {
        const int d = db * 32 + c;
        bf16x8 vb = *(const bf16x8*)((const char*)s_vt + swzV(d, kc * 32 + hi * 16));
        o[db] = __builtin_amdgcn_mfma_f32_32x32x16_bf16(pa, vb, o[db], 0, 0, 0);
      }
    }
  }
  const float l_row = l_acc + __shfl_xor(l_acc, 32);
  float inv[16];
  #pragma unroll
  for (int j = 0; j < 16; ++j)
    inv[j] = 1.f / __shfl(l_row, (j & 3) + 8 * (j >> 2) + 4 * hi, 64);
  float* op = Og + baseQ + (size_t)(wave * 32) * DH;
  #pragma unroll
  for (int db = 0; db < 4; ++db)
    #pragma unroll
    for (int j = 0; j < 16; ++j) {
      const int row = (j & 3) + 8 * (j >> 2) + 4 * hi;
      op[(size_t)row * DH + db * 32 + c] = o[db][j] * inv[j];
    }
}

extern "C" void kernel_launch(void* const* d_in, const int* in_sizes, int n_in,
                              void* d_out, int out_size, void* d_ws, size_t ws_size,
                              hipStream_t stream) {
  const float* q = (const float*)d_in[0];
  const float* k = (const float*)d_in[1];
  const float* v = (const float*)d_in[2];
  const int* lens = (const int*)d_in[3];
  float* out = (float*)d_out;

  if (ws_size >= OFF_L0) {
    char* W = (char*)d_ws;
    bf16* KbT = (bf16*)(W + OFF_KB);
    bf16* VbT = (bf16*)(W + OFF_VB);
    int*  hdr = (int*)(W + OFF_HDR);
    int*  items = (int*)(W + OFF_ITEMS);
    float* L0 = (float*)(W + OFF_L0);
    float* L1 = (float*)(W + OFF_L1);
    float* Po = (float*)(W + OFF_PO);
    int budget = 0;
    if (ws_size >= OFF_PO + PO_STRIDE)
      budget = (int)((ws_size - OFF_PO) / PO_STRIDE);
    if (budget > 32) budget = 32;
    hipLaunchKernelGGL(conv_kv, dim3(4096), dim3(256), 0, stream,
                       k, v, lens, KbT, VbT, hdr, items, budget);
    hipLaunchKernelGGL(fa_dyn, dim3(768), dim3(256), 0, stream,
                       q, lens, out, KbT, VbT, items, hdr, L0, L1, Po);
    hipLaunchKernelGGL(combine, dim3(1024), dim3(256), 0, stream,
                       out, hdr, L0, L1, Po);
  } else {
    hipLaunchKernelGGL(fa_fwd_sync, dim3(BATCH * (QLEN / QBLK)), dim3(256),
                       0, stream, q, k, v, lens, out);
  }
}